// Round 2
// baseline (374.233 us; speedup 1.0000x reference)
//
#include <hip/hip_runtime.h>
#include <hip/hip_bf16.h>
#include <cstdint>

#define S_LEN 2048
#define DIM   256
#define NBAT  8
#define NEDGE 65536
#define HID   512
#define INDIM 768

// ---- workspace layout (bytes) ----
#define OFF_AGG   0u
#define OFF_POOL  16777216u
#define OFF_CNT   16785408u
#define OFF_NODES 16785664u
#define OFF_PRED  17834240u
#define OFF_ROLE  18358528u
#define OFF_W1P   18392576u
#define OFF_W2P   19179008u
#define OFF_FWD   19441152u
#define OFF_REV   19703296u
#define ZERO_BYTES 16785664u   // agg + pooled + counters

typedef short bshort8 __attribute__((ext_vector_type(8)));
typedef float floatx4 __attribute__((ext_vector_type(4)));
typedef ushort ushort4v __attribute__((ext_vector_type(4)));

__device__ __forceinline__ float gelu_f(float x) {
  return 0.5f * x * (1.0f + erff(x * 0.70710678118654752f));
}
__device__ __forceinline__ ushort f2bf(float v) {
  __hip_bfloat16 h = __float2bfloat16(v);
  return *reinterpret_cast<ushort*>(&h);
}

// ---------------- prep: zero ws + f32 tables -> bf16 + pack weights ----------------
#define Z4 1049104   // ZERO_BYTES/16
#define T4 200832    // (nodes+pred+role f32)/4
#define WN 524288    // w1+w2 elements
__global__ void prep_all(const float* __restrict__ pos, const float* __restrict__ pred,
                         const float* __restrict__ role,
                         const float* __restrict__ w1, const float* __restrict__ w2,
                         unsigned char* __restrict__ ws) {
  int i = blockIdx.x * blockDim.x + threadIdx.x;
  if (i < Z4) {
    reinterpret_cast<float4*>(ws)[i] = float4{0.f, 0.f, 0.f, 0.f};
    return;
  }
  i -= Z4;
  if (i < T4) {
    const int NN4 = 131072, NP4 = 65536;
    float4 v;
    if (i < NN4) v = reinterpret_cast<const float4*>(pos)[i];
    else if (i < NN4 + NP4) v = reinterpret_cast<const float4*>(pred)[i - NN4];
    else v = reinterpret_cast<const float4*>(role)[i - NN4 - NP4];
    ushort4v h;
    h.x = f2bf(v.x); h.y = f2bf(v.y); h.z = f2bf(v.z); h.w = f2bf(v.w);
    *reinterpret_cast<ushort4v*>((ushort*)(ws + OFF_NODES) + (i << 2)) = h;
    return;
  }
  i -= T4;
  if (i < WN) {
    ushort* W1p = (ushort*)(ws + OFF_W1P);
    ushort* W2p = (ushort*)(ws + OFF_W2P);
    const int N1 = INDIM * HID;           // 393216
    if (i < N1) {
      int k = i >> 9, n = i & 511;
      W1p[(((k >> 3) << 9) + n) * 8 + (k & 7)] = f2bf(w1[i]);
    } else {
      int j = i - N1;
      int k = j >> 8, n = j & 255;
      W2p[(((k >> 3) << 8) + n) * 8 + (k & 7)] = f2bf(w2[j]);
    }
  }
}

// ---------------- worklist build ----------------
__global__ void build_lists(const int* __restrict__ mask, const int* __restrict__ is_role,
                            const int* __restrict__ add_rev,
                            int* __restrict__ fwd, int* __restrict__ rev, int* __restrict__ cnt) {
  int e = blockIdx.x * blockDim.x + threadIdx.x;
  if (e >= NEDGE) return;
  if (mask[e]) {
    int p = atomicAdd(&cnt[0], 1);
    fwd[p] = e;
    if (!is_role[e] && add_rev[e]) {
      int q = atomicAdd(&cnt[1], 1);
      rev[q] = e;
    }
  }
}

// ---------------- fused edge MLP + scatter ----------------
// 64 rows/tile, 512 threads (8 waves, 2x4 wave grid), swapped-operand MFMA.
// X fragments come straight from L2 (unified table T); only H lives in LDS.
#define HSTR_E 520   // ushort elements per H row (1040 B)
__global__ __launch_bounds__(512, 4)
void mlp_kernel(const int* __restrict__ cnt, const int* __restrict__ fwd, const int* __restrict__ rev,
                const int* __restrict__ a0, const int* __restrict__ a1,
                const int* __restrict__ pred_idx, const int* __restrict__ role_idx,
                const int* __restrict__ is_role,
                const ushort* __restrict__ T,      // nodes|pred|role contiguous (bf16)
                const ushort* __restrict__ W1p, const ushort* __restrict__ W2p,
                const float* __restrict__ b1, const float* __restrict__ b2,
                float* __restrict__ agg) {
  __shared__ ushort Hs[64 * HSTR_E];
  __shared__ int ltgt[64];
  __shared__ int lbat[64];
  __shared__ uint loff[64][3];

  const int tid = threadIdx.x;
  const int nf = cnt[0], nr = cnt[1];
  const int total = nf + nr;
  const int row0 = blockIdx.x * 64;
  if (row0 >= total) return;

  if (tid < 64) {
    int grow = row0 + tid;
    int tgt = -1, bb = 0; uint o0 = 0, o1 = 0, o2 = 0;
    if (grow < total) {
      bool rv = grow >= nf;
      int e = rv ? rev[grow - nf] : fwd[grow];
      bb = e >> 13;
      int A0 = a0[e], A1 = a1[e];
      o1 = 524288u + ((uint)pred_idx[e] << 8);
      if (rv)              { o0 = (uint)A1 << 8; o2 = (uint)A0 << 8;                      tgt = A0; }
      else if (is_role[e]) { o0 = (uint)A0 << 8; o2 = 786432u + ((uint)role_idx[e] << 8); tgt = A0; }
      else                 { o0 = (uint)A0 << 8; o2 = (uint)A1 << 8;                      tgt = A1; }
    }
    ltgt[tid] = tgt; lbat[tid] = bb;
    loff[tid][0] = o0; loff[tid][1] = o1; loff[tid][2] = o2;
  }
  __syncthreads();

  const int lane = tid & 63, wave = tid >> 6;
  const int wm = wave >> 2, wn = wave & 3;
  const int l15 = lane & 15, kb = lane >> 4;
  const int m0 = wm * 32 + l15;
  const int m1 = m0 + 16;

  const uint o00 = loff[m0][0], o01 = loff[m0][1], o02 = loff[m0][2];
  const uint o10 = loff[m1][0], o11 = loff[m1][1], o12 = loff[m1][2];

  // --- GEMM1 (swapped): H^T tile; lane: col=m (l15), rows=n (kb*4+rg) ---
  floatx4 acc1[2][8];
#pragma unroll
  for (int fm = 0; fm < 2; ++fm)
#pragma unroll
    for (int fn = 0; fn < 8; ++fn) acc1[fm][fn] = (floatx4){0.f, 0.f, 0.f, 0.f};

  const int kcb = kb * 8;
  bshort8 xb0 = *reinterpret_cast<const bshort8*>(T + o00 + kcb);
  bshort8 xb1 = *reinterpret_cast<const bshort8*>(T + o10 + kcb);
#pragma unroll 1
  for (int k0 = 0; k0 < INDIM; k0 += 32) {
    // prefetch next k-block's X fragments (last iter reads a harmless valid addr)
    int k1 = k0 + 32;
    uint po0 = (k1 < 256) ? o00 : (k1 < 512) ? o01 : o02;
    uint po1 = (k1 < 256) ? o10 : (k1 < 512) ? o11 : o12;
    int kc1 = (k1 & 255) + kcb;
    bshort8 nx0 = *reinterpret_cast<const bshort8*>(T + po0 + kc1);
    bshort8 nx1 = *reinterpret_cast<const bshort8*>(T + po1 + kc1);

    const ushort* wp = W1p + ((((k0 >> 3) + kb) << 9) + wn * 128 + l15) * 8;
#pragma unroll
    for (int fn = 0; fn < 8; ++fn) {
      bshort8 wv = *reinterpret_cast<const bshort8*>(wp + (fn << 7));
      acc1[0][fn] = __builtin_amdgcn_mfma_f32_16x16x32_bf16(wv, xb0, acc1[0][fn], 0, 0, 0);
      acc1[1][fn] = __builtin_amdgcn_mfma_f32_16x16x32_bf16(wv, xb1, acc1[1][fn], 0, 0, 0);
    }
    xb0 = nx0; xb1 = nx1;
  }

  // --- bias + gelu -> H row-major in LDS, 8B packed writes ---
#pragma unroll
  for (int fm = 0; fm < 2; ++fm) {
    int m = fm ? m1 : m0;
#pragma unroll
    for (int fn = 0; fn < 8; ++fn) {
      int n0 = wn * 128 + fn * 16 + kb * 4;
      float4 bb4 = *reinterpret_cast<const float4*>(b1 + n0);
      ushort4v hv;
      hv.x = f2bf(gelu_f(acc1[fm][fn][0] + bb4.x));
      hv.y = f2bf(gelu_f(acc1[fm][fn][1] + bb4.y));
      hv.z = f2bf(gelu_f(acc1[fm][fn][2] + bb4.z));
      hv.w = f2bf(gelu_f(acc1[fm][fn][3] + bb4.w));
      *reinterpret_cast<ushort4v*>(Hs + m * HSTR_E + n0) = hv;
    }
  }
  __syncthreads();

  // --- GEMM2 (swapped): msg^T; lane: col=m (l15), rows=n (kb*4+rg) ---
  floatx4 acc2[2][4];
#pragma unroll
  for (int fm = 0; fm < 2; ++fm)
#pragma unroll
    for (int fn = 0; fn < 4; ++fn) acc2[fm][fn] = (floatx4){0.f, 0.f, 0.f, 0.f};

#pragma unroll 1
  for (int k0 = 0; k0 < HID; k0 += 32) {
    bshort8 hb0 = *reinterpret_cast<const bshort8*>(Hs + m0 * HSTR_E + k0 + kcb);
    bshort8 hb1 = *reinterpret_cast<const bshort8*>(Hs + m1 * HSTR_E + k0 + kcb);
    const ushort* wp2 = W2p + ((((k0 >> 3) + kb) << 8) + wn * 64 + l15) * 8;
#pragma unroll
    for (int fn = 0; fn < 4; ++fn) {
      bshort8 wv = *reinterpret_cast<const bshort8*>(wp2 + (fn << 7));
      acc2[0][fn] = __builtin_amdgcn_mfma_f32_16x16x32_bf16(wv, hb0, acc2[0][fn], 0, 0, 0);
      acc2[1][fn] = __builtin_amdgcn_mfma_f32_16x16x32_bf16(wv, hb1, acc2[1][fn], 0, 0, 0);
    }
  }

  // --- scatter: per lane 4 consecutive f32 atomics into agg[b][tgt][:] ---
#pragma unroll
  for (int fm = 0; fm < 2; ++fm) {
    int m = fm ? m1 : m0;
    int tgt = ltgt[m];
    if (tgt >= 0) {
      float* dst = agg + ((((uint)lbat[m] << 11) + (uint)tgt) << 8);
#pragma unroll
      for (int fn = 0; fn < 4; ++fn) {
        int n0 = wn * 64 + fn * 16 + kb * 4;
        float4 bb4 = *reinterpret_cast<const float4*>(b2 + n0);
        unsafeAtomicAdd(dst + n0 + 0, acc2[fm][fn][0] + bb4.x);
        unsafeAtomicAdd(dst + n0 + 1, acc2[fm][fn][1] + bb4.y);
        unsafeAtomicAdd(dst + n0 + 2, acc2[fm][fn][2] + bb4.z);
        unsafeAtomicAdd(dst + n0 + 3, acc2[fm][fn][3] + bb4.w);
      }
    }
  }
}

// ---------------- LayerNorm + mean pool ----------------
__global__ void ln_pool(const float* __restrict__ pos, const float* __restrict__ agg,
                        const float* __restrict__ g, const float* __restrict__ be,
                        float* __restrict__ pooled_sum) {
  __shared__ float r2[16];
  const int b = blockIdx.x >> 7;
  const int sb = blockIdx.x & 127;
  const int t = threadIdx.x;
  const float gg = g[t], bb = be[t];
  const int wv = t >> 6;
  float psum = 0.f;
#pragma unroll 1
  for (int i = 0; i < 16; ++i) {
    int s = sb * 16 + i;
    float x = pos[s * DIM + t] + agg[((b << 11) + s) * DIM + t];
    float a = x, q = x * x;
#pragma unroll
    for (int o = 32; o > 0; o >>= 1) { a += __shfl_xor(a, o); q += __shfl_xor(q, o); }
    if ((t & 63) == 0) { r2[wv * 2] = a; r2[wv * 2 + 1] = q; }
    __syncthreads();
    a = r2[0] + r2[2] + r2[4] + r2[6];
    q = r2[1] + r2[3] + r2[5] + r2[7];
    __syncthreads();
    float mu = a * (1.f / 256.f);
    float var = q * (1.f / 256.f) - mu * mu;
    float y = (x - mu) * rsqrtf(var + 1e-5f) * gg + bb;
    psum += y;
  }
  unsafeAtomicAdd(&pooled_sum[(b << 8) + t], psum);
}

// ---------------- final tiny MLP: one block per batch row ----------------
__global__ void final_mlp(const float* __restrict__ pooled_sum,
                          const float* __restrict__ lw1, const float* __restrict__ lb1,
                          const float* __restrict__ lw2, const float* __restrict__ lb2,
                          float* __restrict__ out) {
  __shared__ float pl[256];
  __shared__ float hl[256];
  const int r = blockIdx.x, t = threadIdx.x;
  pl[t] = pooled_sum[(r << 8) + t] * (1.f / 2048.f);
  __syncthreads();
  float a = lb1[t];
#pragma unroll 8
  for (int d = 0; d < 256; ++d) a = fmaf(pl[d], lw1[(d << 8) + t], a);
  hl[t] = gelu_f(a);
  __syncthreads();
  float o = lb2[t];
#pragma unroll 8
  for (int d = 0; d < 256; ++d) o = fmaf(hl[d], lw2[(d << 8) + t], o);
  out[(r << 8) + t] = o;
}

extern "C" void kernel_launch(void* const* d_in, const int* in_sizes, int n_in,
                              void* d_out, int out_size, void* d_ws, size_t ws_size,
                              hipStream_t stream) {
  const float* pos_emb  = (const float*)d_in[0];
  const float* pred_emb = (const float*)d_in[1];
  const float* role_emb = (const float*)d_in[2];
  const float* w1   = (const float*)d_in[3];
  const float* b1   = (const float*)d_in[4];
  const float* w2   = (const float*)d_in[5];
  const float* b2   = (const float*)d_in[6];
  const float* ln_g = (const float*)d_in[7];
  const float* ln_b = (const float*)d_in[8];
  const float* lw1  = (const float*)d_in[9];
  const float* lb1  = (const float*)d_in[10];
  const float* lw2  = (const float*)d_in[11];
  const float* lb2  = (const float*)d_in[12];
  const int* pred_idx = (const int*)d_in[13];
  const int* a0       = (const int*)d_in[14];
  const int* a1       = (const int*)d_in[15];
  const int* role_idx = (const int*)d_in[16];
  const int* is_role  = (const int*)d_in[17];
  const int* add_rev  = (const int*)d_in[18];
  const int* mask     = (const int*)d_in[19];

  unsigned char* ws = (unsigned char*)d_ws;
  float*  agg    = (float*)(ws + OFF_AGG);
  float*  pooled = (float*)(ws + OFF_POOL);
  int*    cnt    = (int*)(ws + OFF_CNT);
  ushort* T      = (ushort*)(ws + OFF_NODES);
  ushort* W1p    = (ushort*)(ws + OFF_W1P);
  ushort* W2p    = (ushort*)(ws + OFF_W2P);
  int*    fwd    = (int*)(ws + OFF_FWD);
  int*    rev    = (int*)(ws + OFF_REV);

  prep_all<<<6931, 256, 0, stream>>>(pos_emb, pred_emb, role_emb, w1, w2, ws);
  build_lists<<<256, 256, 0, stream>>>(mask, is_role, add_rev, fwd, rev, cnt);
  mlp_kernel<<<2048, 512, 0, stream>>>(cnt, fwd, rev, a0, a1, pred_idx, role_idx, is_role,
                                       T, W1p, W2p, b1, b2, agg);
  ln_pool<<<1024, 256, 0, stream>>>(pos_emb, agg, ln_g, ln_b, pooled);
  final_mlp<<<8, 256, 0, stream>>>(pooled, lw1, lb1, lw2, lb2, (float*)d_out);
}

// Round 4
// 289.913 us; speedup vs baseline: 1.2908x; 1.2908x over previous
//
#include <hip/hip_runtime.h>
#include <hip/hip_bf16.h>
#include <cstdint>

#define S_LEN 2048
#define DIM   256
#define NBAT  8
#define NEDGE 65536
#define HID   512
#define INDIM 768

// ---- workspace layout (bytes) ----
#define OFF_AGG   0u
#define OFF_POOL  16777216u
#define OFF_CNT   16785408u
#define OFF_NODES 16785664u
#define OFF_PRED  17834240u
#define OFF_ROLE  18358528u
#define OFF_W1P   18392576u
#define OFF_W2P   19179008u
#define OFF_FWD   19441152u
#define OFF_REV   19703296u
#define ZERO_BYTES 16785664u   // agg + pooled + counters

typedef short bshort8 __attribute__((ext_vector_type(8)));
typedef float floatx4 __attribute__((ext_vector_type(4)));
typedef ushort ushort4v __attribute__((ext_vector_type(4)));

__device__ __forceinline__ float gelu_f(float x) {
  return 0.5f * x * (1.0f + erff(x * 0.70710678118654752f));
}
__device__ __forceinline__ ushort f2bf(float v) {
  __hip_bfloat16 h = __float2bfloat16(v);
  return *reinterpret_cast<ushort*>(&h);
}

// ---------------- prep: zero ws + f32 tables -> bf16 + pack weights ----------------
#define Z4 1049104   // ZERO_BYTES/16
#define T4 200832    // (nodes+pred+role f32)/4
#define WN 524288    // w1+w2 elements
__global__ void prep_all(const float* __restrict__ pos, const float* __restrict__ pred,
                         const float* __restrict__ role,
                         const float* __restrict__ w1, const float* __restrict__ w2,
                         unsigned char* __restrict__ ws) {
  int i = blockIdx.x * blockDim.x + threadIdx.x;
  if (i < Z4) {
    reinterpret_cast<float4*>(ws)[i] = float4{0.f, 0.f, 0.f, 0.f};
    return;
  }
  i -= Z4;
  if (i < T4) {
    const int NN4 = 131072, NP4 = 65536;
    float4 v;
    if (i < NN4) v = reinterpret_cast<const float4*>(pos)[i];
    else if (i < NN4 + NP4) v = reinterpret_cast<const float4*>(pred)[i - NN4];
    else v = reinterpret_cast<const float4*>(role)[i - NN4 - NP4];
    ushort4v h;
    h.x = f2bf(v.x); h.y = f2bf(v.y); h.z = f2bf(v.z); h.w = f2bf(v.w);
    *reinterpret_cast<ushort4v*>((ushort*)(ws + OFF_NODES) + (i << 2)) = h;
    return;
  }
  i -= T4;
  if (i < WN) {
    ushort* W1p = (ushort*)(ws + OFF_W1P);
    ushort* W2p = (ushort*)(ws + OFF_W2P);
    const int N1 = INDIM * HID;           // 393216
    if (i < N1) {
      int k = i >> 9, n = i & 511;
      W1p[(((k >> 3) << 9) + n) * 8 + (k & 7)] = f2bf(w1[i]);
    } else {
      int j = i - N1;
      int k = j >> 8, n = j & 255;
      W2p[(((k >> 3) << 8) + n) * 8 + (k & 7)] = f2bf(w2[j]);
    }
  }
}

// ---------------- worklist build: wave-aggregated atomics (2/wave) ----------------
__global__ void build_lists(const int* __restrict__ mask, const int* __restrict__ is_role,
                            const int* __restrict__ add_rev,
                            int* __restrict__ fwd, int* __restrict__ rev, int* __restrict__ cnt) {
  int e = blockIdx.x * blockDim.x + threadIdx.x;
  int lane = threadIdx.x & 63;
  bool c0 = mask[e] != 0;
  bool c1 = c0 && !is_role[e] && add_rev[e];
  unsigned long long b0 = __ballot(c0);
  unsigned long long b1m = __ballot(c1);
  unsigned long long lt = (1ull << lane) - 1ull;
  int base0 = 0, base1 = 0;
  if (lane == 0) {
    base0 = atomicAdd(&cnt[0], __popcll(b0));
    base1 = atomicAdd(&cnt[1], __popcll(b1m));
  }
  base0 = __shfl(base0, 0);
  base1 = __shfl(base1, 0);
  if (c0) fwd[base0 + __popcll(b0 & lt)] = e;
  if (c1) rev[base1 + __popcll(b1m & lt)] = e;
}

// ---------------- fused edge MLP + scatter ----------------
// 64 rows/tile, 512 threads (8 waves, 2x4 wave grid).
// GEMM1 swapped (A=W1, B=X direct from L2); GEMM2 unswapped (A=H from LDS, B=W2)
// so the scatter C-layout is lane=n-column -> coalesced atomics.
#define HSTR_E 520   // ushort elements per H row (1040 B, 16B-aligned)
__global__ __launch_bounds__(512, 4)
void mlp_kernel(const int* __restrict__ cnt, const int* __restrict__ fwd, const int* __restrict__ rev,
                const int* __restrict__ a0, const int* __restrict__ a1,
                const int* __restrict__ pred_idx, const int* __restrict__ role_idx,
                const int* __restrict__ is_role,
                const ushort* __restrict__ T,      // nodes|pred|role contiguous (bf16)
                const ushort* __restrict__ W1p, const ushort* __restrict__ W2p,
                const float* __restrict__ b1, const float* __restrict__ b2,
                float* __restrict__ agg) {
  __shared__ ushort Hs[64 * HSTR_E];
  __shared__ int ltgt[64];
  __shared__ int lbat[64];
  __shared__ uint loff[64][3];

  const int tid = threadIdx.x;
  const int nf = cnt[0], nr = cnt[1];
  const int total = nf + nr;
  const int row0 = blockIdx.x * 64;
  if (row0 >= total) return;

  if (tid < 64) {
    int grow = row0 + tid;
    int tgt = -1, bb = 0; uint o0 = 0, o1 = 0, o2 = 0;
    if (grow < total) {
      bool rv = grow >= nf;
      int e = rv ? rev[grow - nf] : fwd[grow];
      bb = e >> 13;
      int A0 = a0[e], A1 = a1[e];
      o1 = 524288u + ((uint)pred_idx[e] << 8);
      if (rv)              { o0 = (uint)A1 << 8; o2 = (uint)A0 << 8;                      tgt = A0; }
      else if (is_role[e]) { o0 = (uint)A0 << 8; o2 = 786432u + ((uint)role_idx[e] << 8); tgt = A0; }
      else                 { o0 = (uint)A0 << 8; o2 = (uint)A1 << 8;                      tgt = A1; }
    }
    ltgt[tid] = tgt; lbat[tid] = bb;
    loff[tid][0] = o0; loff[tid][1] = o1; loff[tid][2] = o2;
  }
  __syncthreads();

  const int lane = tid & 63, wave = tid >> 6;
  const int wm = wave >> 2, wn = wave & 3;
  const int l15 = lane & 15, kb = lane >> 4;
  const int m0 = wm * 32 + l15;
  const int m1 = m0 + 16;

  const uint o00 = loff[m0][0], o01 = loff[m0][1], o02 = loff[m0][2];
  const uint o10 = loff[m1][0], o11 = loff[m1][1], o12 = loff[m1][2];

  // --- GEMM1 (swapped): H^T tile; lane: col=m (l15), rows=n (kb*4+rg) ---
  floatx4 acc1[2][8];
#pragma unroll
  for (int fm = 0; fm < 2; ++fm)
#pragma unroll
    for (int fn = 0; fn < 8; ++fn) acc1[fm][fn] = (floatx4){0.f, 0.f, 0.f, 0.f};

  const int kcb = kb * 8;
  bshort8 xb0 = *reinterpret_cast<const bshort8*>(T + o00 + kcb);
  bshort8 xb1 = *reinterpret_cast<const bshort8*>(T + o10 + kcb);
#pragma unroll 1
  for (int k0 = 0; k0 < INDIM; k0 += 32) {
    // prefetch next k-block's X fragments (last iter reads a harmless valid addr)
    int k1 = k0 + 32;
    uint po0 = (k1 < 256) ? o00 : (k1 < 512) ? o01 : o02;
    uint po1 = (k1 < 256) ? o10 : (k1 < 512) ? o11 : o12;
    int kc1 = (k1 & 255) + kcb;
    bshort8 nx0 = *reinterpret_cast<const bshort8*>(T + po0 + kc1);
    bshort8 nx1 = *reinterpret_cast<const bshort8*>(T + po1 + kc1);

    const ushort* wp = W1p + ((((k0 >> 3) + kb) << 9) + wn * 128 + l15) * 8;
#pragma unroll
    for (int fn = 0; fn < 8; ++fn) {
      bshort8 wv = *reinterpret_cast<const bshort8*>(wp + (fn << 7));
      acc1[0][fn] = __builtin_amdgcn_mfma_f32_16x16x32_bf16(wv, xb0, acc1[0][fn], 0, 0, 0);
      acc1[1][fn] = __builtin_amdgcn_mfma_f32_16x16x32_bf16(wv, xb1, acc1[1][fn], 0, 0, 0);
    }
    xb0 = nx0; xb1 = nx1;
  }

  // --- bias + gelu -> H row-major in LDS, 8B packed writes ---
#pragma unroll
  for (int fm = 0; fm < 2; ++fm) {
    int m = fm ? m1 : m0;
#pragma unroll
    for (int fn = 0; fn < 8; ++fn) {
      int n0 = wn * 128 + fn * 16 + kb * 4;
      float4 bb4 = *reinterpret_cast<const float4*>(b1 + n0);
      ushort4v hv;
      hv.x = f2bf(gelu_f(acc1[fm][fn][0] + bb4.x));
      hv.y = f2bf(gelu_f(acc1[fm][fn][1] + bb4.y));
      hv.z = f2bf(gelu_f(acc1[fm][fn][2] + bb4.z));
      hv.w = f2bf(gelu_f(acc1[fm][fn][3] + bb4.w));
      *reinterpret_cast<ushort4v*>(Hs + m * HSTR_E + n0) = hv;
    }
  }
  __syncthreads();

  // --- GEMM2 (unswapped): A = H rows from LDS, B = W2p; C: lane = n col ---
  floatx4 acc2[2][4];
#pragma unroll
  for (int fm = 0; fm < 2; ++fm)
#pragma unroll
    for (int fn = 0; fn < 4; ++fn) acc2[fm][fn] = (floatx4){0.f, 0.f, 0.f, 0.f};

#pragma unroll 1
  for (int k0 = 0; k0 < HID; k0 += 32) {
    bshort8 ha0 = *reinterpret_cast<const bshort8*>(Hs + m0 * HSTR_E + k0 + kcb);
    bshort8 ha1 = *reinterpret_cast<const bshort8*>(Hs + m1 * HSTR_E + k0 + kcb);
    const ushort* wp2 = W2p + ((((k0 >> 3) + kb) << 8) + wn * 64 + l15) * 8;
#pragma unroll
    for (int fn = 0; fn < 4; ++fn) {
      bshort8 wv = *reinterpret_cast<const bshort8*>(wp2 + (fn << 7));
      acc2[0][fn] = __builtin_amdgcn_mfma_f32_16x16x32_bf16(ha0, wv, acc2[0][fn], 0, 0, 0);
      acc2[1][fn] = __builtin_amdgcn_mfma_f32_16x16x32_bf16(ha1, wv, acc2[1][fn], 0, 0, 0);
    }
  }

  // --- scatter: coalesced — 16 consecutive lanes write 16 consecutive floats ---
#pragma unroll
  for (int fn = 0; fn < 4; ++fn) {
    int n = wn * 64 + fn * 16 + l15;
    float bias = b2[n];
#pragma unroll
    for (int fm = 0; fm < 2; ++fm) {
#pragma unroll
      for (int rg = 0; rg < 4; ++rg) {
        int m = wm * 32 + fm * 16 + kb * 4 + rg;
        int tgt = ltgt[m];
        if (tgt >= 0) {
          unsafeAtomicAdd(agg + ((((uint)lbat[m] << 11) + (uint)tgt) << 8) + n,
                          acc2[fm][fn][rg] + bias);
        }
      }
    }
  }
}

// ---------------- LayerNorm + mean pool ----------------
__global__ void ln_pool(const float* __restrict__ pos, const float* __restrict__ agg,
                        const float* __restrict__ g, const float* __restrict__ be,
                        float* __restrict__ pooled_sum) {
  __shared__ float r2[16];
  const int b = blockIdx.x >> 7;
  const int sb = blockIdx.x & 127;
  const int t = threadIdx.x;
  const float gg = g[t], bb = be[t];
  const int wv = t >> 6;
  float psum = 0.f;
#pragma unroll 1
  for (int i = 0; i < 16; ++i) {
    int s = sb * 16 + i;
    float x = pos[s * DIM + t] + agg[((b << 11) + s) * DIM + t];
    float a = x, q = x * x;
#pragma unroll
    for (int o = 32; o > 0; o >>= 1) { a += __shfl_xor(a, o); q += __shfl_xor(q, o); }
    if ((t & 63) == 0) { r2[wv * 2] = a; r2[wv * 2 + 1] = q; }
    __syncthreads();
    a = r2[0] + r2[2] + r2[4] + r2[6];
    q = r2[1] + r2[3] + r2[5] + r2[7];
    __syncthreads();
    float mu = a * (1.f / 256.f);
    float var = q * (1.f / 256.f) - mu * mu;
    float y = (x - mu) * rsqrtf(var + 1e-5f) * gg + bb;
    psum += y;
  }
  unsafeAtomicAdd(&pooled_sum[(b << 8) + t], psum);
}

// ---------------- final tiny MLP: one block per batch row ----------------
__global__ void final_mlp(const float* __restrict__ pooled_sum,
                          const float* __restrict__ lw1, const float* __restrict__ lb1,
                          const float* __restrict__ lw2, const float* __restrict__ lb2,
                          float* __restrict__ out) {
  __shared__ float pl[256];
  __shared__ float hl[256];
  const int r = blockIdx.x, t = threadIdx.x;
  pl[t] = pooled_sum[(r << 8) + t] * (1.f / 2048.f);
  __syncthreads();
  float a = lb1[t];
#pragma unroll 8
  for (int d = 0; d < 256; ++d) a = fmaf(pl[d], lw1[(d << 8) + t], a);
  hl[t] = gelu_f(a);
  __syncthreads();
  float o = lb2[t];
#pragma unroll 8
  for (int d = 0; d < 256; ++d) o = fmaf(hl[d], lw2[(d << 8) + t], o);
  out[(r << 8) + t] = o;
}

extern "C" void kernel_launch(void* const* d_in, const int* in_sizes, int n_in,
                              void* d_out, int out_size, void* d_ws, size_t ws_size,
                              hipStream_t stream) {
  const float* pos_emb  = (const float*)d_in[0];
  const float* pred_emb = (const float*)d_in[1];
  const float* role_emb = (const float*)d_in[2];
  const float* w1   = (const float*)d_in[3];
  const float* b1   = (const float*)d_in[4];
  const float* w2   = (const float*)d_in[5];
  const float* b2   = (const float*)d_in[6];
  const float* ln_g = (const float*)d_in[7];
  const float* ln_b = (const float*)d_in[8];
  const float* lw1  = (const float*)d_in[9];
  const float* lb1  = (const float*)d_in[10];
  const float* lw2  = (const float*)d_in[11];
  const float* lb2  = (const float*)d_in[12];
  const int* pred_idx = (const int*)d_in[13];
  const int* a0       = (const int*)d_in[14];
  const int* a1       = (const int*)d_in[15];
  const int* role_idx = (const int*)d_in[16];
  const int* is_role  = (const int*)d_in[17];
  const int* add_rev  = (const int*)d_in[18];
  const int* mask     = (const int*)d_in[19];

  unsigned char* ws = (unsigned char*)d_ws;
  float*  agg    = (float*)(ws + OFF_AGG);
  float*  pooled = (float*)(ws + OFF_POOL);
  int*    cnt    = (int*)(ws + OFF_CNT);
  ushort* T      = (ushort*)(ws + OFF_NODES);
  ushort* W1p    = (ushort*)(ws + OFF_W1P);
  ushort* W2p    = (ushort*)(ws + OFF_W2P);
  int*    fwd    = (int*)(ws + OFF_FWD);
  int*    rev    = (int*)(ws + OFF_REV);

  prep_all<<<6931, 256, 0, stream>>>(pos_emb, pred_emb, role_emb, w1, w2, ws);
  build_lists<<<256, 256, 0, stream>>>(mask, is_role, add_rev, fwd, rev, cnt);
  mlp_kernel<<<2048, 512, 0, stream>>>(cnt, fwd, rev, a0, a1, pred_idx, role_idx, is_role,
                                       T, W1p, W2p, b1, b2, agg);
  ln_pool<<<1024, 256, 0, stream>>>(pos_emb, agg, ln_g, ln_b, pooled);
  final_mlp<<<8, 256, 0, stream>>>(pooled, lw1, lb1, lw2, lb2, (float*)d_out);
}